// Round 14
// baseline (201.953 us; speedup 1.0000x reference)
//
#include <hip/hip_runtime.h>
#include <math.h>

#define B_TOT 65536

typedef __attribute__((ext_vector_type(4))) float f32x4;
typedef __attribute__((ext_vector_type(4))) unsigned int u32x4;
typedef __attribute__((ext_vector_type(8))) __bf16 bf16x8;

// ---- workspace layout (bytes) ----
#define OFF_WLOGT 0u           // bf16 [128][512]  W_logit^T (n-major, k contiguous)
#define OFF_CBIAS 131072u      // f32 [128]
#define OFF_BCAT  131584u      // bf16 [512][576]  B_cat^T  (n-major, k contiguous)
#define OFF_MOTIF 721408u      // f32 [8][64]
#define OFF_LK    723456u      // f32 [8][64]
#define OFF_GK    725504u      // f32 [8][64]
#define OFF_DIFF  1048576u     // bf16 [B][512]
#define OFF_ATTN  68157440u    // bf16 [B][64]
#define OFF_SSQ   76546048u    // f32 [2][B] partial sum-of-squares

__device__ __forceinline__ unsigned short f2bf(float x) {
  union { float f; unsigned int u; } v; v.f = x;
  return (unsigned short)((v.u + 0x7FFFu + ((v.u >> 16) & 1u)) >> 16);
}

__device__ __forceinline__ float bf2f(unsigned short u) {
  union { unsigned int i; float f; } v; v.i = ((unsigned int)u) << 16; return v.f;
}

// fast tanh: 1 - 2/(e^{2x}+1); clamp avoids exp overflow (tanh(15) = 1-2e-13).
__device__ __forceinline__ float fast_tanh(float x) {
  float cx = fminf(fmaxf(x, -15.f), 15.f);
  float e = __expf(2.f * cx);
  return 1.f - 2.f * __builtin_amdgcn_rcpf(e + 1.f);
}

// ---------------- K0a: tiny precompute: lk, gk, motifs, c_bias ----------------
__global__ __launch_bounds__(256) void k0a(
    const float* __restrict__ lm, const float* __restrict__ gm,
    const float* __restrict__ Wkl, const float* __restrict__ bkl,
    const float* __restrict__ Wkg, const float* __restrict__ bkg,
    const float* __restrict__ bq,
    float* __restrict__ lk, float* __restrict__ gk,
    float* __restrict__ motifs, float* __restrict__ cb) {
  int tid = threadIdx.x;
  for (int o = tid; o < 512; o += 256) {
    int m = o >> 6, d = o & 63;
    float s1 = bkl[d], s2 = bkg[d];
    for (int k = 0; k < 64; ++k) {
      s1 += lm[m*64+k] * Wkl[k*64+d];
      s2 += gm[m*64+k] * Wkg[k*64+d];
    }
    lk[o] = s1; gk[o] = s2;
    motifs[o] = lm[o] + gm[o];
  }
  __syncthreads();
  if (tid < 128) {
    int s_ = tid >> 6, h = (tid >> 3) & 7, m = tid & 7;
    const float* K = s_ ? gk : lk;
    float s = 0.f;
    for (int d = 0; d < 64; ++d) s += bq[h*64+d] * K[m*64+d];
    cb[tid] = 0.125f * s;
  }
}

// ---------------- K0b: W_logit^T and B_cat^T (bf16) ----------------
__global__ __launch_bounds__(256) void k0b(
    const float* __restrict__ Wq, const float* __restrict__ Wout,
    const float* __restrict__ lk, const float* __restrict__ gk,
    const float* __restrict__ motifs,
    unsigned short* __restrict__ wlogT, unsigned short* __restrict__ bcatT) {
  int idx = blockIdx.x * 256 + threadIdx.x;
  if (idx >= 65536 + 512*576) return;
  if (idx < 65536) {
    int c = idx >> 9, k = idx & 511;
    int s_ = c >> 6, h = (c >> 3) & 7, m = c & 7;
    const float* K = (s_ ? gk : lk) + m*64;
    const float* wq = Wq + (size_t)k*512 + h*64;
    float s = 0.f;
    for (int d = 0; d < 64; ++d) s += wq[d] * K[d];
    wlogT[(size_t)c*512 + k] = f2bf(0.125f * s);
  } else {
    int i2 = idx - 65536;
    int n = i2 / 576, k = i2 - n*576;
    float v;
    if (k < 512) {
      v = Wout[(size_t)k*512 + n];
    } else {
      int hm = k - 512, h = hm >> 3, m = hm & 7;
      const float* mo = motifs + m*64;
      const float* wo = Wout + (size_t)(512 + h*64)*512 + n;
      v = 0.f;
      for (int d = 0; d < 64; ++d) v += mo[d] * wo[(size_t)d*512];
    }
    bcatT[(size_t)n*576 + k] = f2bf(v);
  }
}

// ---------------- kA: barrier-free gather + direct-fragment logits GEMM + in-register softmax ----------------
// Each wave owns 16 rows end-to-end. A-frags come straight from the gather
// (lane l: row l&15, k = 8*(l>>4)+j — proven MFMA A layout); B-frags read directly
// from wlogT in global (L1/L2-hot 128 KB). NO __syncthreads anywhere.
// Softmax groups: col = n*16 + r16; each 8-col head group = fixed n, fixed r16>>3,
// varying r16&7 -> reduce with shfl_xor masks 1,2,4 ONLY, per n. (round-13 bug fixed)
__global__ __launch_bounds__(256, 4) void kA(
    const float* __restrict__ ent, const float* __restrict__ rel,
    const int* __restrict__ hI, const int* __restrict__ rI, const int* __restrict__ tI,
    const unsigned short* __restrict__ wlogT, const float* __restrict__ cb,
    unsigned short* __restrict__ diffB, unsigned short* __restrict__ attnB) {
  __shared__ unsigned short attnStage[4][16*64];   // 2 KB per wave (wave-private)

  int tid = threadIdx.x;
  int l = tid & 63, wid = tid >> 6;
  int rowBase = (blockIdx.x * 4 + wid) * 16;       // this wave's 16 rows
  int r16 = l & 15;                                 // A-row / B-col lane index
  int kg = l >> 4;                                  // k-group 0..3
  int b = rowBase + r16;

  int hi = hI[b], ri = rI[b], ti = tI[b];
  const float* hp = ent + (size_t)hi * 512;
  const float* tp = ent + (size_t)ti * 512;
  const float* rp = rel + (size_t)ri * 512;
  const unsigned short* wbase = wlogT + (size_t)r16 * 512 + kg * 8;

  f32x4 acc[8] = {};   // col-tiles n=0..7 (static indexing only)

  for (int c = 0; c < 8; ++c) {
    int k0 = c * 64;
    int q0 = k0 + kg*8, q1 = k0 + 32 + kg*8;
    float hv[16], tv[16], rv[16];
    *(float4*)&hv[0]  = *(const float4*)(hp + q0); *(float4*)&hv[4]  = *(const float4*)(hp + q0 + 4);
    *(float4*)&hv[8]  = *(const float4*)(hp + q1); *(float4*)&hv[12] = *(const float4*)(hp + q1 + 4);
    *(float4*)&tv[0]  = *(const float4*)(tp + q0); *(float4*)&tv[4]  = *(const float4*)(tp + q0 + 4);
    *(float4*)&tv[8]  = *(const float4*)(tp + q1); *(float4*)&tv[12] = *(const float4*)(tp + q1 + 4);
    *(float4*)&rv[0]  = *(const float4*)(rp + q0); *(float4*)&rv[4]  = *(const float4*)(rp + q0 + 4);
    *(float4*)&rv[8]  = *(const float4*)(rp + q1); *(float4*)&rv[12] = *(const float4*)(rp + q1 + 4);

    union { bf16x8 v; unsigned short s[8]; } a0, a1;
    union { u32x4 v; unsigned short s[8]; } d0, d1;
    #pragma unroll
    for (int j = 0; j < 8; ++j) {
      float hr0 = hv[j]   + rv[j],   hr1 = hv[8+j] + rv[8+j];
      a0.s[j] = f2bf(hr0 + tv[j]);   d0.s[j] = f2bf(hr0 - tv[j]);
      a1.s[j] = f2bf(hr1 + tv[8+j]); d1.s[j] = f2bf(hr1 - tv[8+j]);
    }
    *(u32x4*)(diffB + (size_t)b*512 + q0) = d0.v;
    *(u32x4*)(diffB + (size_t)b*512 + q1) = d1.v;

    // MFMA: B-frags straight from global (wlogT row = logit col), two K=32 slices
    #pragma unroll
    for (int n = 0; n < 8; ++n) {
      const unsigned short* wp = wbase + (size_t)n*16*512 + k0;
      bf16x8 b0 = *(const bf16x8*)(wp);
      bf16x8 b1 = *(const bf16x8*)(wp + 32);
      acc[n] = __builtin_amdgcn_mfma_f32_16x16x32_bf16(a0.v, b0, acc[n], 0, 0, 0);
      acc[n] = __builtin_amdgcn_mfma_f32_16x16x32_bf16(a1.v, b1, acc[n], 0, 0, 0);
    }
  }

  // softmax in registers. C layout: col = n*16 + r16, row_local = kg*4 + j.
  // Per-head softmax: 8-lane group reduce (masks 1,2,4), per n independently.
  float cbv[8];
  #pragma unroll
  for (int n = 0; n < 8; ++n) cbv[n] = cb[n*16 + r16];

  #pragma unroll
  for (int j = 0; j < 4; ++j) {
    int rloc = kg*4 + j;
    float w[8];
    #pragma unroll
    for (int n = 0; n < 8; ++n) {
      float v = acc[n][j] + cbv[n];
      float mx = v;
      #pragma unroll
      for (int mk = 1; mk < 8; mk <<= 1) mx = fmaxf(mx, __shfl_xor(mx, mk, 64));
      float e = __expf(v - mx);
      float s = e;
      #pragma unroll
      for (int mk = 1; mk < 8; mk <<= 1) s += __shfl_xor(s, mk, 64);
      w[n] = e / s;
    }
    #pragma unroll
    for (int n = 0; n < 4; ++n)
      attnStage[wid][rloc*64 + n*16 + r16] = f2bf(0.5f * (w[n] + w[n+4]));
  }

  // wave-private LDS transpose -> coalesced global store (no s_barrier needed)
  {
    int rr = l >> 2, off = (l & 3) * 16;
    const u32x4* src = (const u32x4*)(&attnStage[wid][rr*64 + off]);
    u32x4 w0 = src[0], w1 = src[1];
    u32x4* dst = (u32x4*)(attnB + (size_t)(rowBase + rr)*64 + off);
    dst[0] = w0; dst[1] = w1;
  }
}

// ---------------- kB: output GEMM, BM=128 BN=256 BK=64, single-buffered, 9 iters ----------------
// 72-short row stride; 56 KB LDS -> 2 blocks/CU; acc=64 VGPR. (round-9/10 proven form)
__global__ __launch_bounds__(512, 4) void kB(
    const unsigned short* __restrict__ diffB, const unsigned short* __restrict__ attnB,
    const unsigned short* __restrict__ bcatT, const float* __restrict__ bout,
    float* __restrict__ ssqPart) {
  __shared__ __align__(16) unsigned short As[128*72];  // 18432 B
  __shared__ __align__(16) unsigned short Bs[256*72];  // 36864 B
  __shared__ float part[128*4];                        // 2048 B  (57344 total)
  int tid = threadIdx.x;
  int l = tid & 63, wid = tid >> 6;
  int wr = wid >> 2, wc = wid & 3;      // 2 x 4 wave grid, per-wave 64x64
  int mblk = blockIdx.x >> 1, nblk = blockIdx.x & 1;
  int rowBase = mblk * 128;
  int colBase = nblk * 256;
  f32x4 acc[4][4] = {};
  int ar = tid >> 2, aq = tid & 3;      // A-stage: row ar (0..127), 16-short group aq
  int bn2 = tid >> 1, half = tid & 1;   // B-stage: row bn2 (0..255), 32-short half

  u32x4 na0, na1, nb0, nb1, nb2, nb3;
  {
    const unsigned short* ap = diffB + (size_t)(rowBase + ar)*512 + aq*16;
    na0 = *(const u32x4*)ap; na1 = *(const u32x4*)(ap + 8);
    const u32x4* src = (const u32x4*)(bcatT + (size_t)(colBase + bn2)*576 + half*32);
    nb0 = src[0]; nb1 = src[1]; nb2 = src[2]; nb3 = src[3];
  }
  for (int ks = 0; ks < 9; ++ks) {
    __syncthreads();   // previous iter's MFMA reads of As/Bs complete
    *(u32x4*)(&As[ar*72 + aq*16])     = na0;
    *(u32x4*)(&As[ar*72 + aq*16 + 8]) = na1;
    {
      unsigned short* bp = &Bs[bn2*72 + half*32];
      *(u32x4*)(bp)      = nb0;
      *(u32x4*)(bp + 8)  = nb1;
      *(u32x4*)(bp + 16) = nb2;
      *(u32x4*)(bp + 24) = nb3;
    }
    __syncthreads();   // tile ks visible in LDS
    // issue next tile's loads (latency hidden under 32 MFMA)
    if (ks < 8) {
      int k0 = (ks + 1) * 64;
      const unsigned short* ap = (k0 < 512)
        ? diffB + (size_t)(rowBase + ar)*512 + k0 + aq*16
        : attnB + (size_t)(rowBase + ar)*64 + aq*16;
      na0 = *(const u32x4*)ap; na1 = *(const u32x4*)(ap + 8);
      const u32x4* src = (const u32x4*)(bcatT + (size_t)(colBase + bn2)*576 + k0 + half*32);
      nb0 = src[0]; nb1 = src[1]; nb2 = src[2]; nb3 = src[3];
    }
    // MFMA on tile ks (BK=64 -> two 32-wide k-frags)
    #pragma unroll
    for (int kf = 0; kf < 2; ++kf) {
      bf16x8 af[4];
      #pragma unroll
      for (int m = 0; m < 4; ++m)
        af[m] = *(const bf16x8*)(&As[(wr*64 + m*16 + (l & 15))*72 + kf*32 + 8*(l >> 4)]);
      #pragma unroll
      for (int n = 0; n < 4; ++n) {
        bf16x8 bfr = *(const bf16x8*)(&Bs[(wc*64 + n*16 + (l & 15))*72 + kf*32 + 8*(l >> 4)]);
        #pragma unroll
        for (int m = 0; m < 4; ++m)
          acc[m][n] = __builtin_amdgcn_mfma_f32_16x16x32_bf16(af[m], bfr, acc[m][n], 0, 0, 0);
      }
    }
  }
  __syncthreads();
  float bo[4];
  #pragma unroll
  for (int n = 0; n < 4; ++n) bo[n] = bout[colBase + wc*64 + n*16 + (l & 15)];
  #pragma unroll
  for (int m = 0; m < 4; ++m) {
    float ss0 = 0.f, ss1 = 0.f, ss2 = 0.f, ss3 = 0.f;
    #pragma unroll
    for (int n = 0; n < 4; ++n) {
      float t0 = fast_tanh(acc[m][n][0] + bo[n]); ss0 += t0*t0;
      float t1 = fast_tanh(acc[m][n][1] + bo[n]); ss1 += t1*t1;
      float t2 = fast_tanh(acc[m][n][2] + bo[n]); ss2 += t2*t2;
      float t3 = fast_tanh(acc[m][n][3] + bo[n]); ss3 += t3*t3;
    }
    #pragma unroll
    for (int mask = 1; mask < 16; mask <<= 1) {
      ss0 += __shfl_xor(ss0, mask, 64);
      ss1 += __shfl_xor(ss1, mask, 64);
      ss2 += __shfl_xor(ss2, mask, 64);
      ss3 += __shfl_xor(ss3, mask, 64);
    }
    if ((l & 15) == 0) {
      int rbase = wr*64 + m*16 + (l >> 4)*4;
      part[(rbase+0)*4 + wc] = ss0;
      part[(rbase+1)*4 + wc] = ss1;
      part[(rbase+2)*4 + wc] = ss2;
      part[(rbase+3)*4 + wc] = ss3;
    }
  }
  __syncthreads();
  if (tid < 128) {
    float s = part[tid*4] + part[tid*4+1] + part[tid*4+2] + part[tid*4+3];
    ssqPart[(size_t)nblk*B_TOT + rowBase + tid] = s;
  }
}

// ---------------- kCD: motif_loss (direct) + score finalize (proven form) ----------------
__global__ __launch_bounds__(256) void kCD(
    const unsigned short* __restrict__ diffB, const unsigned short* __restrict__ attnB,
    const float* __restrict__ motifs, const float* __restrict__ ssqPart,
    const float* __restrict__ advw, const float* __restrict__ advb,
    float* __restrict__ lossOut, float* __restrict__ scoreOut) {
  __shared__ float mo[512];
  int tid = threadIdx.x;
  mo[tid] = motifs[tid];
  mo[tid + 256] = motifs[tid + 256];
  __syncthreads();
  int l = tid & 63;
  int b = blockIdx.x * 4 + (tid >> 6);
  union { u32x4 v; unsigned short s[8]; } dv, av;
  dv.v = *(const u32x4*)(diffB + (size_t)b*512 + l*8);
  int h = l >> 3;
  av.v = *(const u32x4*)(attnB + (size_t)b*64 + h*8);
  float at[8], df[8];
  #pragma unroll
  for (int j = 0; j < 8; ++j) { df[j] = bf2f(dv.s[j]); at[j] = bf2f(av.s[j]); }
  int dbase = (l & 7) * 8;
  float part = 0.f;
  #pragma unroll
  for (int j = 0; j < 8; ++j) {
    float repr = 0.f;
    #pragma unroll
    for (int m = 0; m < 8; ++m) repr += at[m] * mo[m*64 + dbase + j];
    float e = df[j] - repr;
    part += e * e;
  }
  #pragma unroll
  for (int off = 1; off < 64; off <<= 1) part += __shfl_xor(part, off, 64);
  if (l == 0) lossOut[b] = part;
  if (tid < 4) {
    int rb = blockIdx.x * 4 + tid;
    float s = ssqPart[rb] + ssqPart[B_TOT + rb];
    scoreOut[rb] = advw[0] * sqrtf(s) + advb[0];
  }
}

extern "C" void kernel_launch(void* const* d_in, const int* in_sizes, int n_in,
                              void* d_out, int out_size, void* d_ws, size_t ws_size,
                              hipStream_t stream) {
  const float* ent  = (const float*)d_in[0];
  const float* rel  = (const float*)d_in[1];
  // d_in[2..7] (density path) are mathematically dead: softmax(x + const_per_row) == softmax(x)
  const float* lm   = (const float*)d_in[8];
  const float* gm   = (const float*)d_in[9];
  const float* Wq   = (const float*)d_in[10];
  const float* bq   = (const float*)d_in[11];
  const float* Wkl  = (const float*)d_in[12];
  const float* bkl  = (const float*)d_in[13];
  const float* Wkg  = (const float*)d_in[14];
  const float* bkg  = (const float*)d_in[15];
  const float* Wout = (const float*)d_in[16];
  const float* bout = (const float*)d_in[17];
  const float* advw = (const float*)d_in[18];
  const float* advb = (const float*)d_in[19];
  const int* hI = (const int*)d_in[20];
  const int* rI = (const int*)d_in[21];
  const int* tI = (const int*)d_in[22];
  char* ws = (char*)d_ws;
  unsigned short* wlogT = (unsigned short*)(ws + OFF_WLOGT);
  float* cb     = (float*)(ws + OFF_CBIAS);
  unsigned short* bcatT = (unsigned short*)(ws + OFF_BCAT);
  float* motifs = (float*)(ws + OFF_MOTIF);
  float* lk     = (float*)(ws + OFF_LK);
  float* gk     = (float*)(ws + OFF_GK);
  unsigned short* diffB = (unsigned short*)(ws + OFF_DIFF);
  unsigned short* attnB = (unsigned short*)(ws + OFF_ATTN);
  float* ssqPart = (float*)(ws + OFF_SSQ);
  float* scoreOut = (float*)d_out;
  float* lossOut  = (float*)d_out + B_TOT;

  hipLaunchKernelGGL(k0a, dim3(1), dim3(256), 0, stream,
                     lm, gm, Wkl, bkl, Wkg, bkg, bq, lk, gk, motifs, cb);
  hipLaunchKernelGGL(k0b, dim3(1408), dim3(256), 0, stream,
                     Wq, Wout, lk, gk, motifs, wlogT, bcatT);
  hipLaunchKernelGGL(kA, dim3(B_TOT/64), dim3(256), 0, stream,
                     ent, rel, hI, rI, tI, wlogT, cb, diffB, attnB);
  hipLaunchKernelGGL(kB, dim3(B_TOT/128 * 2), dim3(512), 0, stream,
                     diffB, attnB, bcatT, bout, ssqPart);
  hipLaunchKernelGGL(kCD, dim3(B_TOT/4), dim3(256), 0, stream,
                     diffB, attnB, motifs, ssqPart, advw, advb, lossOut, scoreOut);
}

// Round 15
// 146.634 us; speedup vs baseline: 1.3773x; 1.3773x over previous
//
#include <hip/hip_runtime.h>
#include <math.h>

#define B_TOT 65536

typedef __attribute__((ext_vector_type(4))) float f32x4;
typedef __attribute__((ext_vector_type(4))) unsigned int u32x4;
typedef __attribute__((ext_vector_type(8))) __bf16 bf16x8;

// ---- workspace layout (bytes) ----
#define OFF_WLOGT 0u           // bf16 [128][512]  W_logit^T (n-major, k contiguous)
#define OFF_CBIAS 131072u      // f32 [128]
#define OFF_BCAT  131584u      // bf16 [512][576]  B_cat^T  (n-major, k contiguous)
#define OFF_MOTIF 721408u      // f32 [8][64]
#define OFF_LK    723456u      // f32 [8][64]
#define OFF_GK    725504u      // f32 [8][64]
#define OFF_DIFF  1048576u     // bf16 [B][512]
#define OFF_ATTN  68157440u    // bf16 [B][64]
#define OFF_SSQ   76546048u    // f32 [2][B] partial sum-of-squares

__device__ __forceinline__ unsigned short f2bf(float x) {
  union { float f; unsigned int u; } v; v.f = x;
  return (unsigned short)((v.u + 0x7FFFu + ((v.u >> 16) & 1u)) >> 16);
}

__device__ __forceinline__ float bf2f(unsigned short u) {
  union { unsigned int i; float f; } v; v.i = ((unsigned int)u) << 16; return v.f;
}

// fast tanh: 1 - 2/(e^{2x}+1); clamp avoids exp overflow (tanh(15) = 1-2e-13).
__device__ __forceinline__ float fast_tanh(float x) {
  float cx = fminf(fmaxf(x, -15.f), 15.f);
  float e = __expf(2.f * cx);
  return 1.f - 2.f * __builtin_amdgcn_rcpf(e + 1.f);
}

// LDS-only barrier: orders ds ops across the workgroup WITHOUT the compiler's
// implicit s_waitcnt vmcnt(0) drain (which kills in-flight gather prefetch).
__device__ __forceinline__ void lds_barrier() {
  asm volatile("s_waitcnt lgkmcnt(0)" ::: "memory");
  __builtin_amdgcn_s_barrier();
  asm volatile("" ::: "memory");
  __builtin_amdgcn_sched_barrier(0);
}

// ---------------- K0a: tiny precompute: lk, gk, motifs, c_bias ----------------
__global__ __launch_bounds__(256) void k0a(
    const float* __restrict__ lm, const float* __restrict__ gm,
    const float* __restrict__ Wkl, const float* __restrict__ bkl,
    const float* __restrict__ Wkg, const float* __restrict__ bkg,
    const float* __restrict__ bq,
    float* __restrict__ lk, float* __restrict__ gk,
    float* __restrict__ motifs, float* __restrict__ cb) {
  int tid = threadIdx.x;
  for (int o = tid; o < 512; o += 256) {
    int m = o >> 6, d = o & 63;
    float s1 = bkl[d], s2 = bkg[d];
    for (int k = 0; k < 64; ++k) {
      s1 += lm[m*64+k] * Wkl[k*64+d];
      s2 += gm[m*64+k] * Wkg[k*64+d];
    }
    lk[o] = s1; gk[o] = s2;
    motifs[o] = lm[o] + gm[o];
  }
  __syncthreads();
  if (tid < 128) {
    int s_ = tid >> 6, h = (tid >> 3) & 7, m = tid & 7;
    const float* K = s_ ? gk : lk;
    float s = 0.f;
    for (int d = 0; d < 64; ++d) s += bq[h*64+d] * K[m*64+d];
    cb[tid] = 0.125f * s;
  }
}

// ---------------- K0b: W_logit^T and B_cat^T (bf16) ----------------
__global__ __launch_bounds__(256) void k0b(
    const float* __restrict__ Wq, const float* __restrict__ Wout,
    const float* __restrict__ lk, const float* __restrict__ gk,
    const float* __restrict__ motifs,
    unsigned short* __restrict__ wlogT, unsigned short* __restrict__ bcatT) {
  int idx = blockIdx.x * 256 + threadIdx.x;
  if (idx >= 65536 + 512*576) return;
  if (idx < 65536) {
    int c = idx >> 9, k = idx & 511;
    int s_ = c >> 6, h = (c >> 3) & 7, m = c & 7;
    const float* K = (s_ ? gk : lk) + m*64;
    const float* wq = Wq + (size_t)k*512 + h*64;
    float s = 0.f;
    for (int d = 0; d < 64; ++d) s += wq[d] * K[d];
    wlogT[(size_t)c*512 + k] = f2bf(0.125f * s);
  } else {
    int i2 = idx - 65536;
    int n = i2 / 576, k = i2 - n*576;
    float v;
    if (k < 512) {
      v = Wout[(size_t)k*512 + n];
    } else {
      int hm = k - 512, h = hm >> 3, m = hm & 7;
      const float* mo = motifs + m*64;
      const float* wo = Wout + (size_t)(512 + h*64)*512 + n;
      v = 0.f;
      for (int d = 0; d < 64; ++d) v += mo[d] * wo[(size_t)d*512];
    }
    bcatT[(size_t)n*576 + k] = f2bf(v);
  }
}

// ---------------- kA: fused gather + logits GEMM + softmax -> diffB, attnB ----------------
// 64 rows/block, 256 threads (4 waves, 2x2 wave grid), K streamed in 8 chunks of 64.
// round-12 proven form (LDS-only barriers). launch_bounds min-waves 4->2: license the
// register allocator to keep the 12-load gather prefetch live (r10-r14 all allocated
// only 52-64 VGPR and serialized the gather; occupancy stays LDS-limited ~4 blocks/CU).
__global__ __launch_bounds__(256, 2) void kA(
    const float* __restrict__ ent, const float* __restrict__ rel,
    const int* __restrict__ hI, const int* __restrict__ rI, const int* __restrict__ tI,
    const unsigned short* __restrict__ wlogT, const float* __restrict__ cb,
    unsigned short* __restrict__ diffB, unsigned short* __restrict__ attnB) {
  __shared__ __align__(16) unsigned char smem[32768];
  unsigned short* As = (unsigned short*)smem;               // [64][72] bf16 ctx chunk
  unsigned short* Bs = (unsigned short*)(smem + 9216);      // [128][72] bf16 wlog chunk
  float* lg  = (float*)smem;                                // [64][128] f32 (epilogue alias)

  int tid = threadIdx.x;
  int l = tid & 63, wid = tid >> 6;
  int wr = wid >> 1, wc = wid & 1;
  int rowBase = blockIdx.x * 64;
  int r_loc = tid >> 2, p = tid & 3;
  int b = rowBase + r_loc;

  int hi = hI[b], ri = rI[b], ti = tI[b];
  const float* hp = ent + (size_t)hi * 512;
  const float* tp = ent + (size_t)ti * 512;
  const float* rp = rel + (size_t)ri * 512;
  int bn = tid >> 1, half = tid & 1;
  const unsigned short* wsrc = wlogT + (size_t)bn * 512 + half * 32;

  f32x4 acc[2][4] = {};

  float4 gh[4], gt[4], gr[4];
  u32x4 wb[4];

  // prefetch chunk 0
  {
    int q0 = p*8, q1 = 32 + p*8;
    gh[0] = *(const float4*)(hp + q0); gh[1] = *(const float4*)(hp + q0 + 4);
    gh[2] = *(const float4*)(hp + q1); gh[3] = *(const float4*)(hp + q1 + 4);
    gt[0] = *(const float4*)(tp + q0); gt[1] = *(const float4*)(tp + q0 + 4);
    gt[2] = *(const float4*)(tp + q1); gt[3] = *(const float4*)(tp + q1 + 4);
    gr[0] = *(const float4*)(rp + q0); gr[1] = *(const float4*)(rp + q0 + 4);
    gr[2] = *(const float4*)(rp + q1); gr[3] = *(const float4*)(rp + q1 + 4);
    #pragma unroll
    for (int o = 0; o < 4; ++o) wb[o] = *(const u32x4*)(wsrc + o*8);
  }

  #pragma unroll
  for (int c = 0; c < 8; ++c) {
    int k0 = c * 64;
    union { u32x4 v[2]; unsigned short s[16]; } pd, pc;
    #pragma unroll
    for (int g = 0; g < 4; ++g) {
      #pragma unroll
      for (int j = 0; j < 4; ++j) {
        float hv = ((const float*)&gh[g])[j];
        float tv = ((const float*)&gt[g])[j];
        float rv = ((const float*)&gr[g])[j];
        pd.s[g*4+j] = f2bf(hv + rv - tv);
        pc.s[g*4+j] = f2bf(hv + rv + tv);
      }
    }

    lds_barrier();     // prior chunk's LDS reads complete (LDS-only: no vmcnt drain)
    *(u32x4*)(As + r_loc*72 + p*8)      = pc.v[0];
    *(u32x4*)(As + r_loc*72 + 32 + p*8) = pc.v[1];
    {
      unsigned short* bp = Bs + bn*72 + half*32;
      *(u32x4*)(bp)      = wb[0];
      *(u32x4*)(bp + 8)  = wb[1];
      *(u32x4*)(bp + 16) = wb[2];
      *(u32x4*)(bp + 24) = wb[3];
    }
    *(u32x4*)(diffB + (size_t)b*512 + k0 + p*8)      = pd.v[0];
    *(u32x4*)(diffB + (size_t)b*512 + k0 + 32 + p*8) = pd.v[1];
    lds_barrier();     // As/Bs visible (diff store + prefetch stay in flight)
    if (c < 7) {
      int q0 = k0 + 64 + p*8, q1 = k0 + 96 + p*8;
      gh[0] = *(const float4*)(hp + q0); gh[1] = *(const float4*)(hp + q0 + 4);
      gh[2] = *(const float4*)(hp + q1); gh[3] = *(const float4*)(hp + q1 + 4);
      gt[0] = *(const float4*)(tp + q0); gt[1] = *(const float4*)(tp + q0 + 4);
      gt[2] = *(const float4*)(tp + q1); gt[3] = *(const float4*)(tp + q1 + 4);
      gr[0] = *(const float4*)(rp + q0); gr[1] = *(const float4*)(rp + q0 + 4);
      gr[2] = *(const float4*)(rp + q1); gr[3] = *(const float4*)(rp + q1 + 4);
      #pragma unroll
      for (int o = 0; o < 4; ++o) wb[o] = *(const u32x4*)(wsrc + (c+1)*64 + o*8);
    }
    #pragma unroll
    for (int kf = 0; kf < 2; ++kf) {
      bf16x8 af0 = *(const bf16x8*)(As + (wr*32 +      (l & 15))*72 + kf*32 + 8*(l >> 4));
      bf16x8 af1 = *(const bf16x8*)(As + (wr*32 + 16 + (l & 15))*72 + kf*32 + 8*(l >> 4));
      #pragma unroll
      for (int n = 0; n < 4; ++n) {
        bf16x8 bfr = *(const bf16x8*)(Bs + (wc*64 + n*16 + (l & 15))*72 + kf*32 + 8*(l >> 4));
        acc[0][n] = __builtin_amdgcn_mfma_f32_16x16x32_bf16(af0, bfr, acc[0][n], 0, 0, 0);
        acc[1][n] = __builtin_amdgcn_mfma_f32_16x16x32_bf16(af1, bfr, acc[1][n], 0, 0, 0);
      }
    }
  }

  lds_barrier();    // all MFMA reads done before lg (aliases As/Bs)
  #pragma unroll
  for (int m = 0; m < 2; ++m)
    #pragma unroll
    for (int n = 0; n < 4; ++n)
      #pragma unroll
      for (int j = 0; j < 4; ++j) {
        int rr = wr*32 + m*16 + 4*(l >> 4) + j;
        int cc = wc*64 + n*16 + (l & 15);
        lg[rr*128 + ((cc + rr) & 127)] = acc[m][n][j];
      }
  lds_barrier();

  // epilogue: thread (r_loc, p) handles heads 2p, 2p+1
  #pragma unroll
  for (int e = 0; e < 2; ++e) {
    int h = 2*p + e;
    float a8[8];
    #pragma unroll
    for (int m = 0; m < 8; ++m) a8[m] = 0.f;
    #pragma unroll
    for (int s = 0; s < 2; ++s) {
      float v[8], mx = -1e30f;
      #pragma unroll
      for (int m = 0; m < 8; ++m) {
        int cc = s*64 + h*8 + m;
        v[m] = lg[r_loc*128 + ((cc + r_loc) & 127)] + cb[cc];
        mx = fmaxf(mx, v[m]);
      }
      float sum = 0.f;
      #pragma unroll
      for (int m = 0; m < 8; ++m) { v[m] = __expf(v[m] - mx); sum += v[m]; }
      float inv = 0.5f / sum;
      #pragma unroll
      for (int m = 0; m < 8; ++m) a8[m] += v[m] * inv;
    }
    union { u32x4 v; unsigned short s[8]; } pk;
    #pragma unroll
    for (int m = 0; m < 8; ++m) pk.s[m] = f2bf(a8[m]);
    *(u32x4*)(attnB + (size_t)b*64 + h*8) = pk.v;
  }
}

// ---------------- kB: output GEMM, BM=128 BN=256 BK=64, single-buffered, 9 iters ----------------
// 72-short row stride; 56 KB LDS -> 2 blocks/CU; acc=64 VGPR. (round-9/10 proven form)
__global__ __launch_bounds__(512, 4) void kB(
    const unsigned short* __restrict__ diffB, const unsigned short* __restrict__ attnB,
    const unsigned short* __restrict__ bcatT, const float* __restrict__ bout,
    float* __restrict__ ssqPart) {
  __shared__ __align__(16) unsigned short As[128*72];  // 18432 B
  __shared__ __align__(16) unsigned short Bs[256*72];  // 36864 B
  __shared__ float part[128*4];                        // 2048 B  (57344 total)
  int tid = threadIdx.x;
  int l = tid & 63, wid = tid >> 6;
  int wr = wid >> 2, wc = wid & 3;      // 2 x 4 wave grid, per-wave 64x64
  int mblk = blockIdx.x >> 1, nblk = blockIdx.x & 1;
  int rowBase = mblk * 128;
  int colBase = nblk * 256;
  f32x4 acc[4][4] = {};
  int ar = tid >> 2, aq = tid & 3;      // A-stage: row ar (0..127), 16-short group aq
  int bn2 = tid >> 1, half = tid & 1;   // B-stage: row bn2 (0..255), 32-short half

  u32x4 na0, na1, nb0, nb1, nb2, nb3;
  {
    const unsigned short* ap = diffB + (size_t)(rowBase + ar)*512 + aq*16;
    na0 = *(const u32x4*)ap; na1 = *(const u32x4*)(ap + 8);
    const u32x4* src = (const u32x4*)(bcatT + (size_t)(colBase + bn2)*576 + half*32);
    nb0 = src[0]; nb1 = src[1]; nb2 = src[2]; nb3 = src[3];
  }
  for (int ks = 0; ks < 9; ++ks) {
    __syncthreads();   // previous iter's MFMA reads of As/Bs complete
    *(u32x4*)(&As[ar*72 + aq*16])     = na0;
    *(u32x4*)(&As[ar*72 + aq*16 + 8]) = na1;
    {
      unsigned short* bp = &Bs[bn2*72 + half*32];
      *(u32x4*)(bp)      = nb0;
      *(u32x4*)(bp + 8)  = nb1;
      *(u32x4*)(bp + 16) = nb2;
      *(u32x4*)(bp + 24) = nb3;
    }
    __syncthreads();   // tile ks visible in LDS
    // issue next tile's loads (latency hidden under 32 MFMA)
    if (ks < 8) {
      int k0 = (ks + 1) * 64;
      const unsigned short* ap = (k0 < 512)
        ? diffB + (size_t)(rowBase + ar)*512 + k0 + aq*16
        : attnB + (size_t)(rowBase + ar)*64 + aq*16;
      na0 = *(const u32x4*)ap; na1 = *(const u32x4*)(ap + 8);
      const u32x4* src = (const u32x4*)(bcatT + (size_t)(colBase + bn2)*576 + k0 + half*32);
      nb0 = src[0]; nb1 = src[1]; nb2 = src[2]; nb3 = src[3];
    }
    // MFMA on tile ks (BK=64 -> two 32-wide k-frags)
    #pragma unroll
    for (int kf = 0; kf < 2; ++kf) {
      bf16x8 af[4];
      #pragma unroll
      for (int m = 0; m < 4; ++m)
        af[m] = *(const bf16x8*)(&As[(wr*64 + m*16 + (l & 15))*72 + kf*32 + 8*(l >> 4)]);
      #pragma unroll
      for (int n = 0; n < 4; ++n) {
        bf16x8 bfr = *(const bf16x8*)(&Bs[(wc*64 + n*16 + (l & 15))*72 + kf*32 + 8*(l >> 4)]);
        #pragma unroll
        for (int m = 0; m < 4; ++m)
          acc[m][n] = __builtin_amdgcn_mfma_f32_16x16x32_bf16(af[m], bfr, acc[m][n], 0, 0, 0);
      }
    }
  }
  __syncthreads();
  float bo[4];
  #pragma unroll
  for (int n = 0; n < 4; ++n) bo[n] = bout[colBase + wc*64 + n*16 + (l & 15)];
  #pragma unroll
  for (int m = 0; m < 4; ++m) {
    float ss0 = 0.f, ss1 = 0.f, ss2 = 0.f, ss3 = 0.f;
    #pragma unroll
    for (int n = 0; n < 4; ++n) {
      float t0 = fast_tanh(acc[m][n][0] + bo[n]); ss0 += t0*t0;
      float t1 = fast_tanh(acc[m][n][1] + bo[n]); ss1 += t1*t1;
      float t2 = fast_tanh(acc[m][n][2] + bo[n]); ss2 += t2*t2;
      float t3 = fast_tanh(acc[m][n][3] + bo[n]); ss3 += t3*t3;
    }
    #pragma unroll
    for (int mask = 1; mask < 16; mask <<= 1) {
      ss0 += __shfl_xor(ss0, mask, 64);
      ss1 += __shfl_xor(ss1, mask, 64);
      ss2 += __shfl_xor(ss2, mask, 64);
      ss3 += __shfl_xor(ss3, mask, 64);
    }
    if ((l & 15) == 0) {
      int rbase = wr*64 + m*16 + (l >> 4)*4;
      part[(rbase+0)*4 + wc] = ss0;
      part[(rbase+1)*4 + wc] = ss1;
      part[(rbase+2)*4 + wc] = ss2;
      part[(rbase+3)*4 + wc] = ss3;
    }
  }
  __syncthreads();
  if (tid < 128) {
    float s = part[tid*4] + part[tid*4+1] + part[tid*4+2] + part[tid*4+3];
    ssqPart[(size_t)nblk*B_TOT + rowBase + tid] = s;
  }
}

// ---------------- kCD: motif_loss (direct) + score finalize (proven form) ----------------
__global__ __launch_bounds__(256) void kCD(
    const unsigned short* __restrict__ diffB, const unsigned short* __restrict__ attnB,
    const float* __restrict__ motifs, const float* __restrict__ ssqPart,
    const float* __restrict__ advw, const float* __restrict__ advb,
    float* __restrict__ lossOut, float* __restrict__ scoreOut) {
  __shared__ float mo[512];
  int tid = threadIdx.x;
  mo[tid] = motifs[tid];
  mo[tid + 256] = motifs[tid + 256];
  __syncthreads();
  int l = tid & 63;
  int b = blockIdx.x * 4 + (tid >> 6);
  union { u32x4 v; unsigned short s[8]; } dv, av;
  dv.v = *(const u32x4*)(diffB + (size_t)b*512 + l*8);
  int h = l >> 3;
  av.v = *(const u32x4*)(attnB + (size_t)b*64 + h*8);
  float at[8], df[8];
  #pragma unroll
  for (int j = 0; j < 8; ++j) { df[j] = bf2f(dv.s[j]); at[j] = bf2f(av.s[j]); }
  int dbase = (l & 7) * 8;
  float part = 0.f;
  #pragma unroll
  for (int j = 0; j < 8; ++j) {
    float repr = 0.f;
    #pragma unroll
    for (int m = 0; m < 8; ++m) repr += at[m] * mo[m*64 + dbase + j];
    float e = df[j] - repr;
    part += e * e;
  }
  #pragma unroll
  for (int off = 1; off < 64; off <<= 1) part += __shfl_xor(part, off, 64);
  if (l == 0) lossOut[b] = part;
  if (tid < 4) {
    int rb = blockIdx.x * 4 + tid;
    float s = ssqPart[rb] + ssqPart[B_TOT + rb];
    scoreOut[rb] = advw[0] * sqrtf(s) + advb[0];
  }
}

extern "C" void kernel_launch(void* const* d_in, const int* in_sizes, int n_in,
                              void* d_out, int out_size, void* d_ws, size_t ws_size,
                              hipStream_t stream) {
  const float* ent  = (const float*)d_in[0];
  const float* rel  = (const float*)d_in[1];
  // d_in[2..7] (density path) are mathematically dead: softmax(x + const_per_row) == softmax(x)
  const float* lm   = (const float*)d_in[8];
  const float* gm   = (const float*)d_in[9];
  const float* Wq   = (const float*)d_in[10];
  const float* bq   = (const float*)d_in[11];
  const float* Wkl  = (const float*)d_in[12];
  const float* bkl  = (const float*)d_in[13];
  const float* Wkg  = (const float*)d_in[14];
  const float* bkg  = (const float*)d_in[15];
  const float* Wout = (const float*)d_in[16];
  const float* bout = (const float*)d_in[17];
  const float* advw = (const float*)d_in[18];
  const float* advb = (const float*)d_in[19];
  const int* hI = (const int*)d_in[20];
  const int* rI = (const int*)d_in[21];
  const int* tI = (const int*)d_in[22];
  char* ws = (char*)d_ws;
  unsigned short* wlogT = (unsigned short*)(ws + OFF_WLOGT);
  float* cb     = (float*)(ws + OFF_CBIAS);
  unsigned short* bcatT = (unsigned short*)(ws + OFF_BCAT);
  float* motifs = (float*)(ws + OFF_MOTIF);
  float* lk     = (float*)(ws + OFF_LK);
  float* gk     = (float*)(ws + OFF_GK);
  unsigned short* diffB = (unsigned short*)(ws + OFF_DIFF);
  unsigned short* attnB = (unsigned short*)(ws + OFF_ATTN);
  float* ssqPart = (float*)(ws + OFF_SSQ);
  float* scoreOut = (float*)d_out;
  float* lossOut  = (float*)d_out + B_TOT;

  hipLaunchKernelGGL(k0a, dim3(1), dim3(256), 0, stream,
                     lm, gm, Wkl, bkl, Wkg, bkg, bq, lk, gk, motifs, cb);
  hipLaunchKernelGGL(k0b, dim3(1408), dim3(256), 0, stream,
                     Wq, Wout, lk, gk, motifs, wlogT, bcatT);
  hipLaunchKernelGGL(kA, dim3(B_TOT/64), dim3(256), 0, stream,
                     ent, rel, hI, rI, tI, wlogT, cb, diffB, attnB);
  hipLaunchKernelGGL(kB, dim3(B_TOT/128 * 2), dim3(512), 0, stream,
                     diffB, attnB, bcatT, bout, ssqPart);
  hipLaunchKernelGGL(kCD, dim3(B_TOT/4), dim3(256), 0, stream,
                     diffB, attnB, motifs, ssqPart, advw, advb, lossOut, scoreOut);
}